// Round 3
// baseline (132.070 us; speedup 1.0000x reference)
//
#include <hip/hip_runtime.h>
#include <hip/hip_bf16.h>

// Problem-fixed shapes: features [4,64,2048] fp32 (feats[m][c] = flat[c*8192+m]),
// labels [8192] int32, NUM_CLASSES=4, TEMP=0.07, scalar fp32 out.
#define M_TOT 8192
#define NCLS 4
#define NSEL_CAP 4096   // nsel ~ 3000 (sd ~27); cap 4096 is a >25-sigma guard
#define NST 32          // 32 super-tiles of 128 cover NSEL_CAP

// ---------------- JAX threefry-2x32, key = PRNGKey(42) = (0, 42) -------------
__device__ __forceinline__ unsigned int rotl32(unsigned int x, unsigned int r) {
    return (x << r) | (x >> (32u - r));
}

__device__ unsigned int threefry_bits_key42(unsigned int m) {
    const unsigned int ks0 = 0u;
    const unsigned int ks1 = 42u;
    const unsigned int ks2 = 0x1BD11BDAu ^ 0u ^ 42u;
    unsigned int j  = (m < 4096u) ? m : (m - 4096u);
    unsigned int x0 = j + ks0;
    unsigned int x1 = (j + 4096u) + ks1;
#define TF_RND(r) { x0 += x1; x1 = rotl32(x1, (r)); x1 ^= x0; }
    TF_RND(13u) TF_RND(15u) TF_RND(26u) TF_RND(6u)
    x0 += ks1; x1 += ks2 + 1u;
    TF_RND(17u) TF_RND(29u) TF_RND(16u) TF_RND(24u)
    x0 += ks2; x1 += ks0 + 2u;
    TF_RND(13u) TF_RND(15u) TF_RND(26u) TF_RND(6u)
    x0 += ks0; x1 += ks1 + 3u;
    TF_RND(17u) TF_RND(29u) TF_RND(16u) TF_RND(24u)
    x0 += ks1; x1 += ks2 + 4u;
    TF_RND(13u) TF_RND(15u) TF_RND(26u) TF_RND(6u)
    x0 += ks2; x1 += ks0 + 5u;
#undef TF_RND
    return (m < 4096u) ? x0 : x1;
}

// ---------------- kernel 1a: parallel histogram partials + zero pos/neg ------
// 8 blocks x 256 threads, 4 labels/thread. Partials (no atomics) to hist_part.
__global__ void hist_kernel(const int* __restrict__ labels,
                            int* __restrict__ hist_part,
                            float* __restrict__ pos,
                            float* __restrict__ neg) {
    __shared__ int lhist[NCLS];
    const int t = threadIdx.x;
    const int gid = blockIdx.x * 256 + t;
    for (int i = gid; i < M_TOT; i += 2048) { pos[i] = 0.0f; neg[i] = 0.0f; }
    if (t < NCLS) lhist[t] = 0;
    __syncthreads();

    const int base = blockIdx.x * 1024 + t * 4;
    int c0 = 0, c1 = 0, c2 = 0, c3 = 0;
    #pragma unroll
    for (int r = 0; r < 4; ++r) {
        const int lab = labels[base + r];
        c0 += (lab == 0); c1 += (lab == 1); c2 += (lab == 2); c3 += (lab == 3);
    }
    int cc[4] = {c0, c1, c2, c3};
    const int lane = t & 63;
    #pragma unroll
    for (int cls = 0; cls < NCLS; ++cls) {
        int v = cc[cls];
        for (int off = 32; off > 0; off >>= 1) v += __shfl_down(v, off, 64);
        if (lane == 0) atomicAdd(&lhist[cls], v);
    }
    __syncthreads();
    if (t < NCLS) hist_part[blockIdx.x * NCLS + t] = lhist[t];
}

// ---------------- kernel 1b: keep_p, threefry selection, scan, compaction ----
__global__ void select_kernel(const int* __restrict__ labels,
                              const int* __restrict__ hist_part,
                              int* __restrict__ nsel_g,
                              int* __restrict__ sel_idx,
                              int* __restrict__ lab_sel) {
    __shared__ float keepp[NCLS];
    __shared__ int   wtot[4];
    const int t = threadIdx.x;
    if (t < NCLS) {
        int s = 0;
        #pragma unroll
        for (int b = 0; b < 8; ++b) s += hist_part[b * NCLS + t];
        keepp[t] = fminf(750.0f / ((float)s + 1.0f), 1.0f);
    }
    __syncthreads();

    // each thread owns 32 contiguous m values
    const int m0 = t * 32;
    unsigned int flags = 0u;
    int cnt = 0;
    for (int r = 0; r < 32; ++r) {
        const int m = m0 + r;
        const unsigned int bits = threefry_bits_key42((unsigned int)m);
        // JAX uniform: bitcast((bits>>9)|0x3F800000) - 1.0, then u < p (strict)
        const float u = __uint_as_float((bits >> 9) | 0x3F800000u) - 1.0f;
        if (u < keepp[labels[m]]) { flags |= (1u << r); ++cnt; }
    }
    // wave-level inclusive scan of cnt
    const int lane = t & 63, w = t >> 6;
    int x = cnt;
    #pragma unroll
    for (int off = 1; off < 64; off <<= 1) {
        const int y = __shfl_up(x, off, 64);
        if (lane >= off) x += y;
    }
    if (lane == 63) wtot[w] = x;
    const int excl = x - cnt;
    __syncthreads();
    int base = excl;
    for (int w2 = 0; w2 < w; ++w2) base += wtot[w2];
    if (t == 0) *nsel_g = wtot[0] + wtot[1] + wtot[2] + wtot[3];
    for (int r = 0; r < 32; ++r) {
        if (flags & (1u << r)) {
            const int m = m0 + r;
            sel_idx[base] = m;
            lab_sel[base] = labels[m];
            ++base;
        }
    }
}

// ---------------- kernel 2: L2-normalize selected rows, store transposed -----
// 8 threads per point (kg = k-block of 8). 128 blocks x 256 = 4096 points x 8.
__global__ void norm_kernel(const float* __restrict__ features,
                            const int* __restrict__ sel_idx,
                            const int* __restrict__ nsel_g,
                            float* __restrict__ nv_t) {
    const int tid = blockIdx.x * 256 + threadIdx.x;
    const int p  = tid >> 3;          // point slot 0..4095
    const int kg = tid & 7;           // k-block of 8
    const int nsel = *nsel_g;
    if (p >= nsel) {                  // zero-pad [nsel, 4096)
        #pragma unroll
        for (int q = 0; q < 8; ++q) nv_t[(kg * 8 + q) * M_TOT + p] = 0.0f;
        return;
    }
    const int m = sel_idx[p];
    float v[8];
    float ss = 0.0f;
    #pragma unroll
    for (int q = 0; q < 8; ++q) {
        v[q] = features[(kg * 8 + q) * M_TOT + m];
        ss += v[q] * v[q];
    }
    // sum across the 8 lanes sharing this point
    ss += __shfl_xor(ss, 1, 8);
    ss += __shfl_xor(ss, 2, 8);
    ss += __shfl_xor(ss, 4, 8);
    const float rn = rsqrtf(ss);
    #pragma unroll
    for (int q = 0; q < 8; ++q) nv_t[(kg * 8 + q) * M_TOT + p] = v[q] * rn;
}

// ---------------- kernel 3: pairwise exp-sim masked row+col sums -------------
// 128x128 super-tile per block (upper triangle, jt>=it). 4 waves; wave w owns
// 64x64 sub-tile (sub_i=w>>1, sub_j=w&1); active iff jw>=iw (mirror via col
// scatter when jw>iw). 8x8 acc/thread -> 1 B/MAC LDS (vs 2 for 4x4).
#define EXP2_SCALE 20.609929155556605f   // 1/(0.07*ln2): exp(s/T)=exp2(s*this)

__global__ __launch_bounds__(256, 2) void pair_kernel(
        const float* __restrict__ nv_t,
        const int* __restrict__ lab_sel,
        const int* __restrict__ nsel_g,
        float* __restrict__ pos,
        float* __restrict__ neg) {
    const int it = blockIdx.y, jt = blockIdx.x;
    if (jt < it) return;
    const int nsel = *nsel_g;
    const int i0 = it * 128, j0 = jt * 128;
    if (i0 >= nsel || j0 >= nsel) return;

    __shared__ float As[64][128];   // [k][i local]
    __shared__ float Bs[64][128];   // [k][j local]
    __shared__ int   La[128], Lb[128];

    const int t = threadIdx.x;
    #pragma unroll
    for (int r = 0; r < 8; ++r) {
        const int idx = r * 256 + t;        // 2048 float4 slots per array
        const int k   = idx >> 5;
        const int c4  = (idx & 31) * 4;
        *(float4*)&As[k][c4] = *(const float4*)&nv_t[k * M_TOT + i0 + c4];
        *(float4*)&Bs[k][c4] = *(const float4*)&nv_t[k * M_TOT + j0 + c4];
    }
    if (t < 128) La[t]       = (i0 + t < nsel)         ? lab_sel[i0 + t]       : -1;
    else         Lb[t - 128] = (j0 + t - 128 < nsel)   ? lab_sel[j0 + t - 128] : -2;
    __syncthreads();

    const int wave = t >> 6, lane = t & 63;
    const int sub_i = wave >> 1, sub_j = wave & 1;
    const int iw = i0 + sub_i * 64, jw = j0 + sub_j * 64;
    // inactive wave: mirror sub-tile handled elsewhere; no barriers after this
    if (jw < iw || iw >= nsel || jw >= nsel) return;

    const int tx = lane & 7, ty = lane >> 3;
    const int ia = sub_i * 64 + ty * 8;     // local row base in super-tile
    const int jb = sub_j * 64 + tx * 8;     // local col base

    float acc[8][8] = {};
    #pragma unroll 8
    for (int k = 0; k < 64; ++k) {
        const float4 a0 = *(const float4*)&As[k][ia];
        const float4 a1 = *(const float4*)&As[k][ia + 4];
        const float4 b0 = *(const float4*)&Bs[k][jb];
        const float4 b1 = *(const float4*)&Bs[k][jb + 4];
        const float av[8] = {a0.x, a0.y, a0.z, a0.w, a1.x, a1.y, a1.z, a1.w};
        const float bv[8] = {b0.x, b0.y, b0.z, b0.w, b1.x, b1.y, b1.z, b1.w};
        #pragma unroll
        for (int aa = 0; aa < 8; ++aa)
            #pragma unroll
            for (int bb = 0; bb < 8; ++bb)
                acc[aa][bb] += av[aa] * bv[bb];
    }

    float pacc[8] = {}, nacc[8] = {}, cp[8] = {}, cn[8] = {};
    #pragma unroll
    for (int aa = 0; aa < 8; ++aa) {
        const int ig = i0 + ia + aa;
        const int Li = La[ia + aa];
        #pragma unroll
        for (int bb = 0; bb < 8; ++bb) {
            const int jg = j0 + jb + bb;
            const bool valid = (ig < nsel) && (jg < nsel) && (ig != jg);
            const float d = valid ? exp2f(acc[aa][bb] * EXP2_SCALE) : 0.0f;
            if (Li == Lb[jb + bb]) { pacc[aa] += d; cp[bb] += d; }
            else                   { nacc[aa] += d; cn[bb] += d; }
        }
    }

    // ---- row sums: reduce across tx (groups of 8 lanes)
    #pragma unroll
    for (int aa = 0; aa < 8; ++aa) {
        float p = pacc[aa], n = nacc[aa];
        for (int off = 4; off > 0; off >>= 1) {
            p += __shfl_down(p, off, 8);
            n += __shfl_down(n, off, 8);
        }
        if (tx == 0) {
            const int ig = i0 + ia + aa;
            if (ig < nsel) {
                atomicAdd(&pos[ig], p);
                atomicAdd(&neg[ig], n);
            }
        }
    }

    // ---- column sums (strict upper sub-tiles): reduce across ty (stride 8)
    if (jw > iw) {
        #pragma unroll
        for (int bb = 0; bb < 8; ++bb) {
            float p = cp[bb], n = cn[bb];
            for (int off = 32; off >= 8; off >>= 1) {
                p += __shfl_down(p, off, 64);
                n += __shfl_down(n, off, 64);
            }
            if (ty == 0) {
                const int jg = j0 + jb + bb;
                if (jg < nsel) {
                    atomicAdd(&pos[jg], p);
                    atomicAdd(&neg[jg], n);
                }
            }
        }
    }
}

// ---------------- kernel 4: final loss reduction -----------------------------
__global__ void loss_kernel(const float* __restrict__ pos,
                            const float* __restrict__ neg,
                            const int* __restrict__ nsel_g,
                            float* __restrict__ out) {
    const int nsel = *nsel_g;
    float s = 0.0f;
    for (int i = threadIdx.x; i < nsel; i += 256) {
        const float fr = pos[i] / (pos[i] + neg[i]);
        s += -logf(fr);
    }
    __shared__ float red[256];
    red[threadIdx.x] = s;
    __syncthreads();
    for (int off = 128; off > 0; off >>= 1) {
        if (threadIdx.x < off) red[threadIdx.x] += red[threadIdx.x + off];
        __syncthreads();
    }
    if (threadIdx.x == 0) out[0] = red[0] / (float)(nsel > 0 ? nsel : 1);
}

// ---------------- launch -----------------------------------------------------
extern "C" void kernel_launch(void* const* d_in, const int* in_sizes, int n_in,
                              void* d_out, int out_size, void* d_ws, size_t ws_size,
                              hipStream_t stream) {
    const float* features = (const float*)d_in[0];
    const int*   labels   = (const int*)d_in[1];
    float*       out      = (float*)d_out;
    char*        ws       = (char*)d_ws;

    int*   nsel_g    = (int*)(ws);
    int*   hist_part = (int*)(ws + 64);                       // 8*4 ints
    int*   sel_idx   = (int*)(ws + 1024);                     // 4096 ints
    int*   lab_sel   = (int*)(ws + 1024 + 16384);             // 4096 ints
    float* pos       = (float*)(ws + 1024 + 32768);           // 8192 fp32
    float* neg       = pos + M_TOT;
    float* nv_t      = (float*)(ws + 1024 + 32768 + 65536);   // 64*8192 fp32 = 2 MiB

    hist_kernel<<<8, 256, 0, stream>>>(labels, hist_part, pos, neg);
    select_kernel<<<1, 256, 0, stream>>>(labels, hist_part, nsel_g, sel_idx, lab_sel);
    norm_kernel<<<128, 256, 0, stream>>>(features, sel_idx, nsel_g, nv_t);
    pair_kernel<<<dim3(NST, NST), 256, 0, stream>>>(nv_t, lab_sel, nsel_g, pos, neg);
    loss_kernel<<<1, 256, 0, stream>>>(pos, neg, nsel_g, out);
}

// Round 4
// 90.303 us; speedup vs baseline: 1.4625x; 1.4625x over previous
//
#include <hip/hip_runtime.h>
#include <hip/hip_bf16.h>

// Problem-fixed shapes: features [4,64,2048] fp32 (feats[m][c] = flat[c*8192+m]),
// labels [8192] int32, NUM_CLASSES=4, TEMP=0.07, scalar fp32 out.
#define M_TOT 8192
#define NCLS 4
#define NSEL_CAP 4096   // nsel ~ 3000 (sd ~27); cap 4096 is a >25-sigma guard
#define NT 64           // 64 tiles of 64 points cover NSEL_CAP

typedef __attribute__((ext_vector_type(8)))  short short8v;  // 8 bf16 = 4 VGPRs
typedef __attribute__((ext_vector_type(16))) float f32x16;   // MFMA 32x32 acc

// ---------------- JAX threefry-2x32, key = PRNGKey(42) = (0, 42) -------------
__device__ __forceinline__ unsigned int rotl32(unsigned int x, unsigned int r) {
    return (x << r) | (x >> (32u - r));
}

__device__ unsigned int threefry_bits_key42(unsigned int m) {
    const unsigned int ks0 = 0u;
    const unsigned int ks1 = 42u;
    const unsigned int ks2 = 0x1BD11BDAu ^ 0u ^ 42u;
    unsigned int j  = (m < 4096u) ? m : (m - 4096u);
    unsigned int x0 = j + ks0;
    unsigned int x1 = (j + 4096u) + ks1;
#define TF_RND(r) { x0 += x1; x1 = rotl32(x1, (r)); x1 ^= x0; }
    TF_RND(13u) TF_RND(15u) TF_RND(26u) TF_RND(6u)
    x0 += ks1; x1 += ks2 + 1u;
    TF_RND(17u) TF_RND(29u) TF_RND(16u) TF_RND(24u)
    x0 += ks2; x1 += ks0 + 2u;
    TF_RND(13u) TF_RND(15u) TF_RND(26u) TF_RND(6u)
    x0 += ks0; x1 += ks1 + 3u;
    TF_RND(17u) TF_RND(29u) TF_RND(16u) TF_RND(24u)
    x0 += ks1; x1 += ks2 + 4u;
    TF_RND(13u) TF_RND(15u) TF_RND(26u) TF_RND(6u)
    x0 += ks2; x1 += ks0 + 5u;
#undef TF_RND
    return (m < 4096u) ? x0 : x1;
}

// bf16 round-to-nearest-even helpers (manual: avoids type plumbing)
__device__ __forceinline__ unsigned short f2bf(float x) {
    const unsigned int u = __float_as_uint(x);
    return (unsigned short)((u + 0x7FFFu + ((u >> 16) & 1u)) >> 16);
}
__device__ __forceinline__ float bf2f(unsigned short b) {
    return __uint_as_float(((unsigned int)b) << 16);
}

// ---------------- kernel 1a: parallel histogram partials + zero pos/neg ------
__global__ void hist_kernel(const int* __restrict__ labels,
                            int* __restrict__ hist_part,
                            float* __restrict__ pos,
                            float* __restrict__ neg) {
    __shared__ int lhist[NCLS];
    const int t = threadIdx.x;
    const int gid = blockIdx.x * 256 + t;
    for (int i = gid; i < M_TOT; i += 2048) { pos[i] = 0.0f; neg[i] = 0.0f; }
    if (t < NCLS) lhist[t] = 0;
    __syncthreads();

    const int base = blockIdx.x * 1024 + t * 4;
    int c0 = 0, c1 = 0, c2 = 0, c3 = 0;
    #pragma unroll
    for (int r = 0; r < 4; ++r) {
        const int lab = labels[base + r];
        c0 += (lab == 0); c1 += (lab == 1); c2 += (lab == 2); c3 += (lab == 3);
    }
    int cc[4] = {c0, c1, c2, c3};
    const int lane = t & 63;
    #pragma unroll
    for (int cls = 0; cls < NCLS; ++cls) {
        int v = cc[cls];
        for (int off = 32; off > 0; off >>= 1) v += __shfl_down(v, off, 64);
        if (lane == 0) atomicAdd(&lhist[cls], v);
    }
    __syncthreads();
    if (t < NCLS) hist_part[blockIdx.x * NCLS + t] = lhist[t];
}

// ---------------- kernel 1b: keep_p, threefry selection, scan, compaction ----
__global__ void select_kernel(const int* __restrict__ labels,
                              const int* __restrict__ hist_part,
                              int* __restrict__ nsel_g,
                              int* __restrict__ sel_idx,
                              int* __restrict__ lab_sel) {
    __shared__ float keepp[NCLS];
    __shared__ int   wtot[4];
    const int t = threadIdx.x;
    if (t < NCLS) {
        int s = 0;
        #pragma unroll
        for (int b = 0; b < 8; ++b) s += hist_part[b * NCLS + t];
        keepp[t] = fminf(750.0f / ((float)s + 1.0f), 1.0f);
    }
    __syncthreads();

    const int m0 = t * 32;
    unsigned int flags = 0u;
    int cnt = 0;
    for (int r = 0; r < 32; ++r) {
        const int m = m0 + r;
        const unsigned int bits = threefry_bits_key42((unsigned int)m);
        // JAX uniform: bitcast((bits>>9)|0x3F800000) - 1.0, then u < p (strict)
        const float u = __uint_as_float((bits >> 9) | 0x3F800000u) - 1.0f;
        if (u < keepp[labels[m]]) { flags |= (1u << r); ++cnt; }
    }
    const int lane = t & 63, w = t >> 6;
    int x = cnt;
    #pragma unroll
    for (int off = 1; off < 64; off <<= 1) {
        const int y = __shfl_up(x, off, 64);
        if (lane >= off) x += y;
    }
    if (lane == 63) wtot[w] = x;
    const int excl = x - cnt;
    __syncthreads();
    int base = excl;
    for (int w2 = 0; w2 < w; ++w2) base += wtot[w2];
    if (t == 0) *nsel_g = wtot[0] + wtot[1] + wtot[2] + wtot[3];
    for (int r = 0; r < 32; ++r) {
        if (flags & (1u << r)) {
            const int m = m0 + r;
            sel_idx[base] = m;
            lab_sel[base] = labels[m];
            ++base;
        }
    }
}

// ---------------- kernel 2: normalize + bf16 hi/lo split, point-major --------
// nv_hi/nv_lo are [4096][64] bf16 (ushort). 8 threads/point.
__global__ void norm_kernel(const float* __restrict__ features,
                            const int* __restrict__ sel_idx,
                            const int* __restrict__ nsel_g,
                            unsigned short* __restrict__ nv_hi,
                            unsigned short* __restrict__ nv_lo) {
    const int tid = blockIdx.x * 256 + threadIdx.x;
    const int p  = tid >> 3;          // point slot 0..4095
    const int kg = tid & 7;           // k-block of 8
    const int nsel = *nsel_g;
    const int ofs = (p << 6) + kg * 8;
    if (p >= nsel) {                  // zero-pad [nsel, 4096)
        const uint4 z = {0, 0, 0, 0};
        *(uint4*)&nv_hi[ofs] = z;
        *(uint4*)&nv_lo[ofs] = z;
        return;
    }
    const int m = sel_idx[p];
    float v[8];
    float ss = 0.0f;
    #pragma unroll
    for (int q = 0; q < 8; ++q) {
        v[q] = features[(kg * 8 + q) * M_TOT + m];
        ss += v[q] * v[q];
    }
    ss += __shfl_xor(ss, 1, 8);
    ss += __shfl_xor(ss, 2, 8);
    ss += __shfl_xor(ss, 4, 8);
    const float rn = rsqrtf(ss);
    unsigned short hs[8], ls[8];
    #pragma unroll
    for (int q = 0; q < 8; ++q) {
        const float x = v[q] * rn;
        const unsigned short h = f2bf(x);
        hs[q] = h;
        ls[q] = f2bf(x - bf2f(h));
    }
    *(uint4*)&nv_hi[ofs] = *(const uint4*)hs;
    *(uint4*)&nv_lo[ofs] = *(const uint4*)ls;
}

// ---------------- kernel 3: MFMA pairwise exp-sim, column sums only ----------
// Full matrix (no triangle): block = 64x64 tile, 4 waves = four 32x32 MFMA
// quadrants. sim in fp32 via bf16 hi/lo split: hi*hi + hi*lo + lo*hi.
// Each block scatters only COLUMN sums (free per-lane adds) -> pos/neg[j].
#define EXP2_SCALE 20.609929155556605f   // 1/(0.07*ln2): exp(s/T)=exp2(s*this)
#define LSTR 72                          // LDS row stride (bf16): 144 B, 16B-aligned

__global__ __launch_bounds__(256, 4) void pair_kernel(
        const unsigned short* __restrict__ nv_hi,
        const unsigned short* __restrict__ nv_lo,
        const int* __restrict__ lab_sel,
        const int* __restrict__ nsel_g,
        float* __restrict__ pos,
        float* __restrict__ neg) {
    const int nsel = *nsel_g;
    const int it = blockIdx.y, jt = blockIdx.x;
    const int i0 = it * 64, j0 = jt * 64;
    if (i0 >= nsel || j0 >= nsel) return;

    __shared__ __align__(16) short sAhi[64][LSTR];
    __shared__ __align__(16) short sAlo[64][LSTR];
    __shared__ __align__(16) short sBhi[64][LSTR];
    __shared__ __align__(16) short sBlo[64][LSTR];
    __shared__ int La[64], Lb[64];

    const int t = threadIdx.x;
    // stage 4 planes: 64 rows x 64 bf16 each; 512 x 16B slots per plane
    for (int idx = t; idx < 512; idx += 256) {
        const int p  = idx >> 3;
        const int kc = (idx & 7) * 8;
        *(uint4*)&sAhi[p][kc] = *(const uint4*)&nv_hi[((i0 + p) << 6) + kc];
        *(uint4*)&sAlo[p][kc] = *(const uint4*)&nv_lo[((i0 + p) << 6) + kc];
        *(uint4*)&sBhi[p][kc] = *(const uint4*)&nv_hi[((j0 + p) << 6) + kc];
        *(uint4*)&sBlo[p][kc] = *(const uint4*)&nv_lo[((j0 + p) << 6) + kc];
    }
    if (t < 64)       La[t]      = lab_sel[i0 + t];        // junk beyond nsel ok (masked)
    else if (t < 128) Lb[t - 64] = lab_sel[j0 + t - 64];
    __syncthreads();

    const int wave = t >> 6, lane = t & 63;
    const int qi = (wave >> 1) * 32, qj = (wave & 1) * 32;
    const int half = lane >> 5, l31 = lane & 31;
    const int ra = qi + l31;          // A-fragment row (local)
    const int rb = qj + l31;          // B-fragment point/col (local)

    f32x16 acc;
    #pragma unroll
    for (int r = 0; r < 16; ++r) acc[r] = 0.0f;

    #pragma unroll
    for (int k0 = 0; k0 < 64; k0 += 16) {
        const int ka = k0 + half * 8;
        const short8v ah = *(const short8v*)&sAhi[ra][ka];
        const short8v al = *(const short8v*)&sAlo[ra][ka];
        const short8v bh = *(const short8v*)&sBhi[rb][ka];
        const short8v bl = *(const short8v*)&sBlo[rb][ka];
        acc = __builtin_amdgcn_mfma_f32_32x32x16_bf16(ah, bh, acc, 0, 0, 0);
        acc = __builtin_amdgcn_mfma_f32_32x32x16_bf16(ah, bl, acc, 0, 0, 0);
        acc = __builtin_amdgcn_mfma_f32_32x32x16_bf16(al, bh, acc, 0, 0, 0);
    }

    // epilogue: C/D layout col=lane&31, row=(reg&3)+8*(reg>>2)+4*(lane>>5)
    const int colL = qj + l31;
    const int jg = j0 + colL;
    const int Lj = Lb[colL];
    float cp = 0.0f, cn = 0.0f;
    #pragma unroll
    for (int r = 0; r < 16; ++r) {
        const int rowL = qi + (r & 3) + 8 * (r >> 2) + 4 * half;
        const int ig = i0 + rowL;
        const bool valid = (ig < nsel) && (jg < nsel) && (ig != jg);
        const float d = valid ? exp2f(acc[r] * EXP2_SCALE) : 0.0f;
        if (La[rowL] == Lj) cp += d; else cn += d;
    }
    // combine the two lane-halves (rows split across halves), then scatter cols
    cp += __shfl_xor(cp, 32, 64);
    cn += __shfl_xor(cn, 32, 64);
    if (half == 0 && jg < nsel) {
        atomicAdd(&pos[jg], cp);
        atomicAdd(&neg[jg], cn);
    }
}

// ---------------- kernel 4: final loss reduction -----------------------------
__global__ void loss_kernel(const float* __restrict__ pos,
                            const float* __restrict__ neg,
                            const int* __restrict__ nsel_g,
                            float* __restrict__ out) {
    const int nsel = *nsel_g;
    float s = 0.0f;
    for (int i = threadIdx.x; i < nsel; i += 256) {
        const float fr = pos[i] / (pos[i] + neg[i]);
        s += -logf(fr);
    }
    __shared__ float red[256];
    red[threadIdx.x] = s;
    __syncthreads();
    for (int off = 128; off > 0; off >>= 1) {
        if (threadIdx.x < off) red[threadIdx.x] += red[threadIdx.x + off];
        __syncthreads();
    }
    if (threadIdx.x == 0) out[0] = red[0] / (float)(nsel > 0 ? nsel : 1);
}

// ---------------- launch -----------------------------------------------------
extern "C" void kernel_launch(void* const* d_in, const int* in_sizes, int n_in,
                              void* d_out, int out_size, void* d_ws, size_t ws_size,
                              hipStream_t stream) {
    const float* features = (const float*)d_in[0];
    const int*   labels   = (const int*)d_in[1];
    float*       out      = (float*)d_out;
    char*        ws       = (char*)d_ws;

    int*   nsel_g    = (int*)(ws);
    int*   hist_part = (int*)(ws + 64);                        // 8*4 ints
    int*   sel_idx   = (int*)(ws + 1024);                      // 4096 ints
    int*   lab_sel   = (int*)(ws + 1024 + 16384);              // 4096 ints
    float* pos       = (float*)(ws + 1024 + 32768);            // 8192 fp32
    float* neg       = pos + M_TOT;
    unsigned short* nv_hi = (unsigned short*)(ws + 1024 + 32768 + 65536);  // 512 KB
    unsigned short* nv_lo = nv_hi + NSEL_CAP * 64;                         // 512 KB

    hist_kernel<<<8, 256, 0, stream>>>(labels, hist_part, pos, neg);
    select_kernel<<<1, 256, 0, stream>>>(labels, hist_part, nsel_g, sel_idx, lab_sel);
    norm_kernel<<<128, 256, 0, stream>>>(features, sel_idx, nsel_g, nv_hi, nv_lo);
    pair_kernel<<<dim3(NT, NT), 256, 0, stream>>>(nv_hi, nv_lo, lab_sel, nsel_g, pos, neg);
    loss_kernel<<<1, 256, 0, stream>>>(pos, neg, nsel_g, out);
}